// Round 1
// baseline (363.392 us; speedup 1.0000x reference)
//
#include <hip/hip_runtime.h>
#include <stdint.h>

// x: [B=16, H=224, W=224, C=64] fp32 NHWC; gating_kernel: [2,2,64,1] fp32
// conv stride 2x2 valid -> g: [16,112,112]; top-K=1254 per batch;
// gate = scatter of top-k values; out = x * gate (broadcast 2x2xC).
#define BATCH   16
#define HDIM    224
#define WDIM    224
#define CDIM    64
#define HO      112
#define WO      112
#define NPATCH  (HO * WO)        // 12544 = 256 * 49
#define KSEL    1254
#define ROWF    (WDIM * CDIM)    // 14336 floats per image row
#define PERTHR  49               // keys per thread in select
#define ROWF4   (WDIM * 16)      // 3584 float4 per image row
#define ACH     7                // float4 chunks per thread in apply
#define ABLK    2                // blocks per image row in apply (3584/(256*7))

typedef float f32x4 __attribute__((ext_vector_type(4)));

// ---------------------------------------------------------------------------
// Kernel 1: gating conv. One patch per half-wave; 2x128 contiguous floats per
// patch, float4 per lane -> wave-level 1KB contiguous loads. Memory-bound:
// 205 MB read @ ~6.3 TB/s ~ 33 us floor.  (unchanged)
// ---------------------------------------------------------------------------
__global__ __launch_bounds__(256) void conv_gate_kernel(
    const float* __restrict__ x, const float* __restrict__ wk,
    float* __restrict__ g) {
  const int tid = threadIdx.x;
  const int lane = tid & 31;
  const int p = blockIdx.x * 8 + (tid >> 5);  // 8 half-waves/block

  const int b   = p / NPATCH;
  const int rem = p - b * NPATCH;
  const int ho  = rem / WO;
  const int wo  = rem - ho * WO;

  const float4 w0 = *reinterpret_cast<const float4*>(wk + lane * 4);
  const float4 w1 = *reinterpret_cast<const float4*>(wk + 128 + lane * 4);

  const long row0 = (long)(b * HDIM + 2 * ho) * ROWF + wo * 128 + lane * 4;
  const float4 a0 = *reinterpret_cast<const float4*>(x + row0);
  const float4 a1 = *reinterpret_cast<const float4*>(x + row0 + ROWF);

  float partial = a0.x * w0.x + a0.y * w0.y + a0.z * w0.z + a0.w * w0.w
                + a1.x * w1.x + a1.y * w1.y + a1.z * w1.z + a1.w * w1.w;

  #pragma unroll
  for (int off = 16; off > 0; off >>= 1)
    partial += __shfl_down(partial, off, 32);

  if (lane == 0) g[p] = partial;
}

// ---------------------------------------------------------------------------
// Kernel 2: exact per-batch top-K. R7 change: radix-4 bitwise search (2 bits
// per round) on order-preserving uint32 keys -> 16 count rounds instead of 32,
// one barrier per round (n1,n2 packed 16+16 in one word, n3 separate;
// double-buffered wave counts, every thread sums redundantly -> uniform T).
// Max block count 12544 < 2^16 so the packing cannot carry across fields.
// Tie handling identical (stable lowest-index).
// ---------------------------------------------------------------------------
__global__ __launch_bounds__(256) void select_kernel(
    const float* __restrict__ g, float* __restrict__ gate) {
  __shared__ int cnt[2][4][2];   // [parity][wave][{packed n1|n2<<16, n3}]
  __shared__ int eq_list[256];
  __shared__ int eq_count;

  const int b = blockIdx.x;
  const int tid = threadIdx.x;
  const float* __restrict__ gb  = g    + b * NPATCH;
  float* __restrict__       gtb = gate + b * NPATCH;

  uint32_t key[PERTHR];
  #pragma unroll
  for (int j = 0; j < PERTHR; ++j) {
    uint32_t u = __float_as_uint(gb[tid + j * 256]);
    key[j] = (u & 0x80000000u) ? ~u : (u | 0x80000000u);  // monotone map
  }
  if (tid == 0) eq_count = 0;

  int par = 0;

  // T = max{t : count(keys >= t) >= K}, built 2 bits per round from the top.
  uint32_t T = 0;
  for (int bit = 30; bit >= 0; bit -= 2) {
    const uint32_t c1 = T | (1u << bit);
    const uint32_t c2 = T | (2u << bit);
    const uint32_t c3 = T | (3u << bit);
    int w = 0, n3 = 0;
    #pragma unroll
    for (int j = 0; j < PERTHR; ++j) {
      const uint32_t k = key[j];
      w  += (k >= c1) ? 1 : 0;
      w  += (k >= c2) ? 0x10000 : 0;
      n3 += (k >= c3) ? 1 : 0;
    }
    #pragma unroll
    for (int off = 32; off > 0; off >>= 1) {
      w  += __shfl_down(w, off, 64);
      n3 += __shfl_down(n3, off, 64);
    }
    if ((tid & 63) == 0) { cnt[par][tid >> 6][0] = w; cnt[par][tid >> 6][1] = n3; }
    __syncthreads();
    const int sw = cnt[par][0][0] + cnt[par][1][0] + cnt[par][2][0] + cnt[par][3][0];
    const int s3 = cnt[par][0][1] + cnt[par][1][1] + cnt[par][2][1] + cnt[par][3][1];
    par ^= 1;
    const int t1 = sw & 0xFFFF;
    const int t2 = (int)(((unsigned)sw) >> 16);
    if      (s3 >= KSEL) T = c3;        // uniform across block
    else if (t2 >= KSEL) T = c2;
    else if (t1 >= KSEL) T = c1;
  }

  // count strictly-greater -> number of threshold-equal elements to keep
  int cg = 0;
  #pragma unroll
  for (int j = 0; j < PERTHR; ++j) cg += (key[j] > T) ? 1 : 0;
  #pragma unroll
  for (int off = 32; off > 0; off >>= 1) cg += __shfl_down(cg, off, 64);
  if ((tid & 63) == 0) cnt[par][tid >> 6][0] = cg;
  __syncthreads();
  const int krem = KSEL -
      (cnt[par][0][0] + cnt[par][1][0] + cnt[par][2][0] + cnt[par][3][0]);

  // dense write pass; gather threshold-equal indices
  #pragma unroll
  for (int j = 0; j < PERTHR; ++j) {
    const int i = tid + j * 256;
    const uint32_t k = key[j];
    float v = 0.0f;
    if (k > T) {
      uint32_t u = (k & 0x80000000u) ? (k & 0x7FFFFFFFu) : ~k;
      v = __uint_as_float(u);
    }
    gtb[i] = v;
    if (k == T) {
      int pos = atomicAdd(&eq_count, 1);
      if (pos < 256) eq_list[pos] = i;
    }
  }
  __syncthreads();

  if (tid == 0) {
    const int ec = eq_count;
    const float tval =
        __uint_as_float((T & 0x80000000u) ? (T & 0x7FFFFFFFu) : ~T);
    if (ec <= 256) {
      for (int i = 0; i < ec; ++i) {          // sort tiny tie list by index
        int mn = i;
        for (int j = i + 1; j < ec; ++j)
          if (eq_list[j] < eq_list[mn]) mn = j;
        int t = eq_list[mn]; eq_list[mn] = eq_list[i]; eq_list[i] = t;
      }
      for (int i = 0; i < ec && i < krem; ++i)
        gtb[eq_list[i]] = tval;
    } else {
      int kept = 0;                            // pathological mass-tie path
      for (int i = 0; i < NPATCH && kept < krem; ++i) {
        uint32_t u = __float_as_uint(gb[i]);
        uint32_t k = (u & 0x80000000u) ? ~u : (u | 0x80000000u);
        if (k == T) { gtb[i] = tval; ++kept; }
      }
    }
  }
}

// ---------------------------------------------------------------------------
// Kernel 3: SPARSE apply. R7 change: 7 float4 per thread (chunks 256 v4 apart
// so every store instruction stays wave-dense 1KB), 7x fewer blocks
// (50176 -> 7168), gate loads hoisted for ILP. 90% of patches gate==0 ->
// write zeros without reading x (x-read only for selected ~20 MB, L3-hit).
// Non-temporal stores for the write-once out stream. ~205 MB write floor.
// ---------------------------------------------------------------------------
__global__ __launch_bounds__(256) void apply_gate_kernel(
    const float* __restrict__ x, const float* __restrict__ gate,
    float* __restrict__ out) {
  const int bi = blockIdx.x;
  const int rowblk = bi & (ABLK - 1);
  const int rowid  = bi >> 1;              // b*224 + h
  const int h = rowid % HDIM;
  const int b = rowid / HDIM;

  const int gbase = b * NPATCH + (h >> 1) * WO;
  const size_t rowoff = (size_t)rowid * ROWF4;
  const int v40 = rowblk * (256 * ACH) + threadIdx.x;

  float gv[ACH];
  #pragma unroll
  for (int k = 0; k < ACH; ++k)
    gv[k] = gate[gbase + ((v40 + k * 256) >> 5)];   // v4>>4=pixel, >>5=patch col

  #pragma unroll
  for (int k = 0; k < ACH; ++k) {
    const size_t v4 = rowoff + v40 + k * 256;
    f32x4 o = {0.0f, 0.0f, 0.0f, 0.0f};
    if (gv[k] != 0.0f) {
      const f32x4 a = *reinterpret_cast<const f32x4*>(x + v4 * 4);
      o = a * gv[k];
    }
    __builtin_nontemporal_store(o, reinterpret_cast<f32x4*>(out + v4 * 4));
  }
}

extern "C" void kernel_launch(void* const* d_in, const int* in_sizes, int n_in,
                              void* d_out, int out_size, void* d_ws, size_t ws_size,
                              hipStream_t stream) {
  const float* x  = (const float*)d_in[0];   // [16,224,224,64]
  const float* wk = (const float*)d_in[1];   // [2,2,64,1]
  float* out = (float*)d_out;

  float* g    = (float*)d_ws;                // [16, 12544]
  float* gate = g + BATCH * NPATCH;          // [16, 12544]

  conv_gate_kernel<<<(BATCH * NPATCH) / 8, 256, 0, stream>>>(x, wk, g);
  select_kernel<<<BATCH, 256, 0, stream>>>(g, gate);
  apply_gate_kernel<<<BATCH * HDIM * ABLK, 256, 0, stream>>>(x, gate, out);
}

// Round 2
// 354.840 us; speedup vs baseline: 1.0241x; 1.0241x over previous
//
#include <hip/hip_runtime.h>
#include <hip/hip_bf16.h>
#include <stdint.h>

// x: [B=16, H=224, W=224, C=64] fp32 NHWC; gating_kernel: [2,2,64,1] fp32
// conv stride 2x2 valid -> g: [16,112,112]; top-K=1254 per batch;
// gate = scatter of top-k values; out = x * gate (broadcast 2x2xC).
#define BATCH   16
#define HDIM    224
#define WDIM    224
#define CDIM    64
#define HO      112
#define WO      112
#define NPATCH  (HO * WO)        // 12544 = 256 * 49
#define KSEL    1254
#define ROWF    (WDIM * CDIM)    // 14336 floats per image row
#define PERTHR  49               // keys per thread in select
#define ROWF4   (WDIM * 16)      // 3584 float4 per image row
#define BLKROW  14               // 3584 / 256 blocks per row in apply

typedef float f32x4 __attribute__((ext_vector_type(4)));

// ---------------------------------------------------------------------------
// Kernel 1: gating conv. One patch per half-wave; 2x128 contiguous floats per
// patch, float4 per lane -> wave-level 1KB contiguous loads. Memory-bound:
// 205 MB read @ ~6.3 TB/s ~ 33 us floor.
// ---------------------------------------------------------------------------
__global__ __launch_bounds__(256) void conv_gate_kernel(
    const float* __restrict__ x, const float* __restrict__ wk,
    float* __restrict__ g) {
  const int tid = threadIdx.x;
  const int lane = tid & 31;
  const int p = blockIdx.x * 8 + (tid >> 5);  // 8 half-waves/block

  const int b   = p / NPATCH;
  const int rem = p - b * NPATCH;
  const int ho  = rem / WO;
  const int wo  = rem - ho * WO;

  const float4 w0 = *reinterpret_cast<const float4*>(wk + lane * 4);
  const float4 w1 = *reinterpret_cast<const float4*>(wk + 128 + lane * 4);

  const long row0 = (long)(b * HDIM + 2 * ho) * ROWF + wo * 128 + lane * 4;
  const float4 a0 = *reinterpret_cast<const float4*>(x + row0);
  const float4 a1 = *reinterpret_cast<const float4*>(x + row0 + ROWF);

  float partial = a0.x * w0.x + a0.y * w0.y + a0.z * w0.z + a0.w * w0.w
                + a1.x * w1.x + a1.y * w1.y + a1.z * w1.z + a1.w * w1.w;

  #pragma unroll
  for (int off = 16; off > 0; off >>= 1)
    partial += __shfl_down(partial, off, 32);

  if (lane == 0) g[p] = partial;
}

// ---------------------------------------------------------------------------
// Kernel 2: exact per-batch top-K via 32-step bitwise binary search on
// order-preserving uint32 keys in registers (49/thread, 256 threads).
// ONE barrier per count round (double-buffered wave counts, every thread
// sums redundantly -> uniform T update), 34 barriers total.
// Tie handling: stable lowest-index.
// ---------------------------------------------------------------------------
__global__ __launch_bounds__(256) void select_kernel(
    const float* __restrict__ g, float* __restrict__ gate) {
  __shared__ int cnt[2][4];
  __shared__ int eq_list[256];
  __shared__ int eq_count;

  const int b = blockIdx.x;
  const int tid = threadIdx.x;
  const float* __restrict__ gb  = g    + b * NPATCH;
  float* __restrict__       gtb = gate + b * NPATCH;

  uint32_t key[PERTHR];
  #pragma unroll
  for (int j = 0; j < PERTHR; ++j) {
    uint32_t u = __float_as_uint(gb[tid + j * 256]);
    key[j] = (u & 0x80000000u) ? ~u : (u | 0x80000000u);  // monotone map
  }
  if (tid == 0) eq_count = 0;

  int par = 0;
  // one-barrier block count: wave-reduce, write cnt[par], barrier, all
  // threads sum the 4 wave totals redundantly (uniform result).
  auto block_count = [&](int c) -> int {
    #pragma unroll
    for (int off = 32; off > 0; off >>= 1) c += __shfl_down(c, off, 64);
    if ((tid & 63) == 0) cnt[par][tid >> 6] = c;
    __syncthreads();
    const int tot = cnt[par][0] + cnt[par][1] + cnt[par][2] + cnt[par][3];
    par ^= 1;
    return tot;
  };

  // T = max{t : count(keys >= t) >= K}, built bit by bit from the top.
  uint32_t T = 0;
  for (int bit = 31; bit >= 0; --bit) {
    const uint32_t cand = T | (1u << bit);
    int c = 0;
    #pragma unroll
    for (int j = 0; j < PERTHR; ++j) c += (key[j] >= cand) ? 1 : 0;
    if (block_count(c) >= KSEL) T = cand;   // uniform across block
  }

  // count strictly-greater -> number of threshold-equal elements to keep
  int cg = 0;
  #pragma unroll
  for (int j = 0; j < PERTHR; ++j) cg += (key[j] > T) ? 1 : 0;
  const int krem = KSEL - block_count(cg);

  // dense write pass; gather threshold-equal indices
  #pragma unroll
  for (int j = 0; j < PERTHR; ++j) {
    const int i = tid + j * 256;
    const uint32_t k = key[j];
    float v = 0.0f;
    if (k > T) {
      uint32_t u = (k & 0x80000000u) ? (k & 0x7FFFFFFFu) : ~k;
      v = __uint_as_float(u);
    }
    gtb[i] = v;
    if (k == T) {
      int pos = atomicAdd(&eq_count, 1);
      if (pos < 256) eq_list[pos] = i;
    }
  }
  __syncthreads();

  if (tid == 0) {
    const int ec = eq_count;
    const float tval =
        __uint_as_float((T & 0x80000000u) ? (T & 0x7FFFFFFFu) : ~T);
    if (ec <= 256) {
      for (int i = 0; i < ec; ++i) {          // sort tiny tie list by index
        int mn = i;
        for (int j = i + 1; j < ec; ++j)
          if (eq_list[j] < eq_list[mn]) mn = j;
        int t = eq_list[mn]; eq_list[mn] = eq_list[i]; eq_list[i] = t;
      }
      for (int i = 0; i < ec && i < krem; ++i)
        gtb[eq_list[i]] = tval;
    } else {
      int kept = 0;                            // pathological mass-tie path
      for (int i = 0; i < NPATCH && kept < krem; ++i) {
        uint32_t u = __float_as_uint(gb[i]);
        uint32_t k = (u & 0x80000000u) ? ~u : (u | 0x80000000u);
        if (k == T) { gtb[i] = tval; ++kept; }
      }
    }
  }
}

// ---------------------------------------------------------------------------
// Kernel 3: SPARSE apply. 90% of patches gate==0 -> write zeros without
// reading x (x-read only for selected ~20 MB, L3-hit). Non-temporal stores
// for the write-once out stream. ~205 MB write floor.
// ---------------------------------------------------------------------------
__global__ __launch_bounds__(256) void apply_gate_kernel(
    const float* __restrict__ x, const float* __restrict__ gate,
    float* __restrict__ out) {
  const int bi = blockIdx.x;
  const int rowblk = bi % BLKROW;
  const int rowid  = bi / BLKROW;          // b*224 + h
  const int h = rowid % HDIM;
  const int b = rowid / HDIM;

  const int v4row = rowblk * 256 + threadIdx.x;
  const int w = v4row >> 4;
  const int gidx = b * NPATCH + (h >> 1) * WO + (w >> 1);

  const float gv = gate[gidx];
  const size_t v4 = (size_t)rowid * ROWF4 + v4row;

  f32x4 o = {0.0f, 0.0f, 0.0f, 0.0f};
  if (gv != 0.0f) {
    const f32x4 a = *reinterpret_cast<const f32x4*>(x + v4 * 4);
    o = a * gv;
  }
  __builtin_nontemporal_store(o, reinterpret_cast<f32x4*>(out + v4 * 4));
}

extern "C" void kernel_launch(void* const* d_in, const int* in_sizes, int n_in,
                              void* d_out, int out_size, void* d_ws, size_t ws_size,
                              hipStream_t stream) {
  const float* x  = (const float*)d_in[0];   // [16,224,224,64]
  const float* wk = (const float*)d_in[1];   // [2,2,64,1]
  float* out = (float*)d_out;

  float* g    = (float*)d_ws;                // [16, 12544]
  float* gate = g + BATCH * NPATCH;          // [16, 12544]

  conv_gate_kernel<<<(BATCH * NPATCH) / 8, 256, 0, stream>>>(x, wk, g);
  select_kernel<<<BATCH, 256, 0, stream>>>(g, gate);
  apply_gate_kernel<<<BATCH * HDIM * BLKROW, 256, 0, stream>>>(x, gate, out);
}

// Round 3
// 343.166 us; speedup vs baseline: 1.0589x; 1.0340x over previous
//
#include <hip/hip_runtime.h>
#include <stdint.h>

// x: [B=16, H=224, W=224, C=64] fp32 NHWC; gating_kernel: [2,2,64,1] fp32
// conv stride 2x2 valid -> g: [16,112,112]; top-K=1254 per batch;
// gate = scatter of top-k values; out = x * gate (broadcast 2x2xC).
#define BATCH   16
#define HDIM    224
#define WDIM    224
#define CDIM    64
#define HO      112
#define WO      112
#define NPATCH  (HO * WO)        // 12544 = 256 * 49
#define KSEL    1254
#define ROWF    (WDIM * CDIM)    // 14336 floats per image row
#define PERTHR  49               // keys per thread in select
#define ROWF4   (WDIM * 16)      // 3584 float4 per image row
#define OUTV4   (BATCH * HDIM * ROWF4)  // 12,845,056 float4 in out
#define ZBLK    3136             // zero-fill blocks: 3136*256*16 == OUTV4
#define ZPT     16               // float4 per zero-fill thread
#define NSELTOT (BATCH * KSEL)   // 20064 selected patches total

typedef float f32x4 __attribute__((ext_vector_type(4)));

// ---------------------------------------------------------------------------
// Kernel 1: gating conv. One patch per half-wave; 2x128 contiguous floats per
// patch, float4 per lane -> wave-level 1KB contiguous loads. Memory-bound:
// 205 MB read @ ~6.3 TB/s ~ 33 us floor.  (unchanged)
// ---------------------------------------------------------------------------
__global__ __launch_bounds__(256) void conv_gate_kernel(
    const float* __restrict__ x, const float* __restrict__ wk,
    float* __restrict__ g) {
  const int tid = threadIdx.x;
  const int lane = tid & 31;
  const int p = blockIdx.x * 8 + (tid >> 5);  // 8 half-waves/block

  const int b   = p / NPATCH;
  const int rem = p - b * NPATCH;
  const int ho  = rem / WO;
  const int wo  = rem - ho * WO;

  const float4 w0 = *reinterpret_cast<const float4*>(wk + lane * 4);
  const float4 w1 = *reinterpret_cast<const float4*>(wk + 128 + lane * 4);

  const long row0 = (long)(b * HDIM + 2 * ho) * ROWF + wo * 128 + lane * 4;
  const float4 a0 = *reinterpret_cast<const float4*>(x + row0);
  const float4 a1 = *reinterpret_cast<const float4*>(x + row0 + ROWF);

  float partial = a0.x * w0.x + a0.y * w0.y + a0.z * w0.z + a0.w * w0.w
                + a1.x * w1.x + a1.y * w1.y + a1.z * w1.z + a1.w * w1.w;

  #pragma unroll
  for (int off = 16; off > 0; off >>= 1)
    partial += __shfl_down(partial, off, 32);

  if (lane == 0) g[p] = partial;
}

// ---------------------------------------------------------------------------
// Kernel 2 (R8): COMBINED select + zero-fill in ONE dispatch so select's
// ~18 us of 16-block latency hides under the ~31 us zero-fill of out.
//   blocks [0,16):    exact per-batch top-K (identical 32-step bitwise
//                     binary search + stable lowest-index ties), emitting a
//                     COMPACT list of (patch_idx, value) pairs per batch.
//   blocks [16,16+ZBLK): zero-fill the whole out buffer (205 MB NT stores).
// The zero region is select-independent; selected patches are overwritten by
// kernel 3 afterward (stream-ordered, cross-dispatch coherent).
// ---------------------------------------------------------------------------
__global__ __launch_bounds__(256) void select_zero_kernel(
    const float* __restrict__ g, uint2* __restrict__ list,
    float* __restrict__ out) {
  const int tid = threadIdx.x;

  if (blockIdx.x >= 16) {
    // ---- zero-fill portion: each thread 16 wave-dense 1KB-stride stores ----
    const int base = (blockIdx.x - 16) * 256 + tid;
    const f32x4 z = {0.0f, 0.0f, 0.0f, 0.0f};
    f32x4* o = reinterpret_cast<f32x4*>(out);
    #pragma unroll
    for (int k = 0; k < ZPT; ++k)
      __builtin_nontemporal_store(z, o + base + (size_t)k * (ZBLK * 256));
    return;
  }

  // ---- select portion: one block per batch image ----
  __shared__ int cnt[2][4];
  __shared__ int eq_list[256];
  __shared__ int eq_count;
  __shared__ int nsel;

  const int b = blockIdx.x;
  const int lane = tid & 63;
  const float* __restrict__ gb = g + b * NPATCH;
  uint2* __restrict__ lb = list + b * KSEL;

  uint32_t key[PERTHR];
  #pragma unroll
  for (int j = 0; j < PERTHR; ++j) {
    uint32_t u = __float_as_uint(gb[tid + j * 256]);
    key[j] = (u & 0x80000000u) ? ~u : (u | 0x80000000u);  // monotone map
  }
  if (tid == 0) { eq_count = 0; nsel = 0; }

  int par = 0;
  // one-barrier block count: wave-reduce, write cnt[par], barrier, all
  // threads sum the 4 wave totals redundantly (uniform result).
  auto block_count = [&](int c) -> int {
    #pragma unroll
    for (int off = 32; off > 0; off >>= 1) c += __shfl_down(c, off, 64);
    if ((tid & 63) == 0) cnt[par][tid >> 6] = c;
    __syncthreads();
    const int tot = cnt[par][0] + cnt[par][1] + cnt[par][2] + cnt[par][3];
    par ^= 1;
    return tot;
  };

  // T = max{t : count(keys >= t) >= K}, built bit by bit from the top.
  uint32_t T = 0;
  for (int bit = 31; bit >= 0; --bit) {
    const uint32_t cand = T | (1u << bit);
    int c = 0;
    #pragma unroll
    for (int j = 0; j < PERTHR; ++j) c += (key[j] >= cand) ? 1 : 0;
    if (block_count(c) >= KSEL) T = cand;   // uniform across block
  }

  // count strictly-greater -> number of threshold-equal elements to keep
  int cg = 0;
  #pragma unroll
  for (int j = 0; j < PERTHR; ++j) cg += (key[j] > T) ? 1 : 0;
  const int krem = KSEL - block_count(cg);

  // append pass: strictly-greater keys -> compact list (ballot per wave);
  // threshold-equal indices -> eq_list for stable lowest-index resolution.
  #pragma unroll
  for (int j = 0; j < PERTHR; ++j) {
    const int i = tid + j * 256;
    const uint32_t k = key[j];
    const bool sel = (k > T);
    const unsigned long long m = __ballot(sel);
    int base;
    if (lane == 0) base = atomicAdd(&nsel, __popcll(m));
    base = __shfl(base, 0, 64);
    if (sel) {
      const int pos = base + __popcll(m & ((1ull << lane) - 1ull));
      const uint32_t u = (k & 0x80000000u) ? (k & 0x7FFFFFFFu) : ~k;
      lb[pos] = make_uint2((uint32_t)i, u);
    }
    if (k == T) {
      int pos = atomicAdd(&eq_count, 1);
      if (pos < 256) eq_list[pos] = i;
    }
  }
  __syncthreads();

  if (tid == 0) {
    const int ec = eq_count;
    const int base2 = KSEL - krem;   // == count strictly-greater
    const uint32_t tbits = (T & 0x80000000u) ? (T & 0x7FFFFFFFu) : ~T;
    if (ec <= 256) {
      for (int i = 0; i < ec; ++i) {          // sort tiny tie list by index
        int mn = i;
        for (int j = i + 1; j < ec; ++j)
          if (eq_list[j] < eq_list[mn]) mn = j;
        int t = eq_list[mn]; eq_list[mn] = eq_list[i]; eq_list[i] = t;
      }
      for (int i = 0; i < ec && i < krem; ++i)
        lb[base2 + i] = make_uint2((uint32_t)eq_list[i], tbits);
    } else {
      int kept = 0;                            // pathological mass-tie path
      for (int i = 0; i < NPATCH && kept < krem; ++i) {
        uint32_t u = __float_as_uint(gb[i]);
        uint32_t k = (u & 0x80000000u) ? ~u : (u | 0x80000000u);
        if (k == T) { lb[base2 + kept] = make_uint2((uint32_t)i, tbits); ++kept; }
      }
    }
  }
}

// ---------------------------------------------------------------------------
// Kernel 3 (R8): compact apply. One 64-lane wave per selected patch
// (exactly 16*1254 = 20064 waves, 5016 blocks). Each wave: read the uniform
// (idx,val) entry, then 2x512B x-read + multiply + 2x512B NT store.
// ~20 MB each way -> ~8-10 us.
// ---------------------------------------------------------------------------
__global__ __launch_bounds__(256) void apply_list_kernel(
    const float* __restrict__ x, const uint2* __restrict__ list,
    float* __restrict__ out) {
  const int wid = blockIdx.x * 4 + (threadIdx.x >> 6);  // wave id = entry id
  const int lane = threadIdx.x & 63;

  const uint2 ent = list[wid];
  const int b   = wid / KSEL;
  const int idx = (int)ent.x;                 // patch index within batch
  const float val = __uint_as_float(ent.y);

  const int ho = idx / WO;
  const int wo = idx - ho * WO;
  const size_t base_v4 = (size_t)(b * HDIM + 2 * ho) * ROWF4 + wo * 32;
  const size_t v4 = base_v4 + (lane < 32 ? (size_t)lane
                                         : (size_t)(ROWF4 + lane - 32));

  const f32x4 a = *reinterpret_cast<const f32x4*>(x + v4 * 4);
  const f32x4 o = a * val;
  __builtin_nontemporal_store(o, reinterpret_cast<f32x4*>(out + v4 * 4));
}

extern "C" void kernel_launch(void* const* d_in, const int* in_sizes, int n_in,
                              void* d_out, int out_size, void* d_ws, size_t ws_size,
                              hipStream_t stream) {
  const float* x  = (const float*)d_in[0];   // [16,224,224,64]
  const float* wk = (const float*)d_in[1];   // [2,2,64,1]
  float* out = (float*)d_out;

  float* g    = (float*)d_ws;                          // [16, 12544] floats
  uint2* list = (uint2*)((char*)d_ws + (size_t)BATCH * NPATCH * 4);  // [16,1254]

  conv_gate_kernel<<<(BATCH * NPATCH) / 8, 256, 0, stream>>>(x, wk, g);
  select_zero_kernel<<<16 + ZBLK, 256, 0, stream>>>(g, list, out);
  apply_list_kernel<<<NSELTOT / 4, 256, 0, stream>>>(x, list, out);
}